// Round 2
// baseline (40528.619 us; speedup 1.0000x reference)
//
#include <hip/hip_runtime.h>
#include <hip/hip_bf16.h>

#define BB 32
#define TD 800
#define TO 400
#define AA 256
#define EE 512
#define VV 8192
#define G4 1024
#define MM (BB*TO)        // 12800
#define NEGE -1e9f
#define KTP 1024          // padded Td for kT

__device__ __forceinline__ float sigm(float x){ return 1.f/(1.f+expf(-x)); }

__device__ __forceinline__ float decode_ptf(const void* p){
  int w = *(const int*)p;
  if (w >= 0 && w < 1048576) return (float)w;   // int-encoded small scalar
  return __int_as_float(w);                      // fp32-encoded
}

// ---- transpose weights: WihcT[a][j]=W_ih[j][512+a], WhhT[a][j]=W_hh[j][a], WihxT[e][j]=W_ih[j][e]
__global__ void kprep_w(const float* __restrict__ Wih, const float* __restrict__ Whh,
                        float* __restrict__ WihcT, float* __restrict__ WhhT,
                        float* __restrict__ WihxT){
  int id = blockIdx.x*blockDim.x + threadIdx.x;
  const int total = AA*G4 + AA*G4 + EE*G4;
  for (; id < total; id += gridDim.x*blockDim.x){
    if (id < AA*G4){
      int a = id >> 10, j = id & 1023;
      WihcT[id] = Wih[j*768 + EE + a];
    } else if (id < 2*AA*G4){
      int i2 = id - AA*G4;
      int a = i2 >> 10, j = i2 & 1023;
      WhhT[i2] = Whh[j*AA + a];
    } else {
      int i2 = id - 2*AA*G4;
      int e = i2 >> 10, j = i2 & 1023;
      WihxT[i2] = Wih[j*768 + e];
    }
  }
}

// ---- kT[b][a][t] = k[b][t][a], zero-padded to t<1024
__global__ void kprep_kT(const float* __restrict__ k, float* __restrict__ kT){
  int id = blockIdx.x*blockDim.x + threadIdx.x;
  const int total = BB*AA*KTP;
  for (; id < total; id += gridDim.x*blockDim.x){
    int t = id & (KTP-1);
    int rest = id >> 10;
    int a = rest & (AA-1);
    int b = rest >> 8;
    kT[id] = (t < TD) ? k[(b*TD + t)*AA + a] : 0.f;
  }
}

// ---- XG[m][j] = sum_e emb[gt[m]][e]*WihxT[e][j] + b_ih[j] + b_hh[j]
__global__ __launch_bounds__(256) void kxg(const int* __restrict__ gt,
                     const float* __restrict__ embW,
                     const float* __restrict__ WihxT, const float* __restrict__ bih,
                     const float* __restrict__ bhh, float* __restrict__ XG){
  __shared__ float Xs[16][64];
  __shared__ int toks[16];
  const int m0 = blockIdx.x * 16;
  const int j0 = blockIdx.y * 256 + (threadIdx.x & 63)*4;
  const int r0 = (threadIdx.x >> 6) * 4;
  float acc[4][4];
  #pragma unroll
  for (int r=0;r<4;++r){ acc[r][0]=acc[r][1]=acc[r][2]=acc[r][3]=0.f; }
  if (threadIdx.x < 16) toks[threadIdx.x] = gt[m0 + threadIdx.x];
  __syncthreads();
  for (int kc=0; kc<EE; kc+=64){
    {
      int lr = threadIdx.x >> 4;     // 0..15 row
      int lq = threadIdx.x & 15;     // 0..15 quad
      const float4 xv = *(const float4*)(embW + (size_t)toks[lr]*EE + kc + lq*4);
      Xs[lr][lq*4+0]=xv.x; Xs[lr][lq*4+1]=xv.y; Xs[lr][lq*4+2]=xv.z; Xs[lr][lq*4+3]=xv.w;
    }
    __syncthreads();
    #pragma unroll 4
    for (int kk=0; kk<64; ++kk){
      const float4 wv = *(const float4*)(WihxT + (size_t)(kc+kk)*G4 + j0);
      #pragma unroll
      for (int r=0;r<4;++r){
        float xs = Xs[r0+r][kk];
        acc[r][0] += wv.x*xs; acc[r][1] += wv.y*xs;
        acc[r][2] += wv.z*xs; acc[r][3] += wv.w*xs;
      }
    }
    __syncthreads();
  }
  const float4 b1 = *(const float4*)(bih + j0);
  const float4 b2 = *(const float4*)(bhh + j0);
  #pragma unroll
  for (int r=0;r<4;++r){
    float4 o4 = make_float4(acc[r][0]+b1.x+b2.x, acc[r][1]+b1.y+b2.y,
                            acc[r][2]+b1.z+b2.z, acc[r][3]+b1.w+b2.w);
    *(float4*)(XG + (size_t)(m0+r0+r)*G4 + j0) = o4;
  }
}

// ---- sequential recurrence, one block per batch element
__global__ __launch_bounds__(1024) void kseq(
    const float* __restrict__ kT, const float* __restrict__ v,
    const int* __restrict__ enc, const int* __restrict__ gt,
    const void* __restrict__ ptfp, const float* __restrict__ embW,
    const float* __restrict__ bih, const float* __restrict__ bhh,
    const float* __restrict__ charb, const float* __restrict__ u,
    const float* __restrict__ XG, const float* __restrict__ WihcT,
    const float* __restrict__ WhhT, const float* __restrict__ WihxT,
    float* __restrict__ HCT)
{
  __shared__ float h_s[AA], c_s[AA], ctx_s[AA];
  __shared__ float g_s[G4];
  __shared__ float p_s[KTP];
  __shared__ float x_s[EE];
  __shared__ float hc_s[EE];
  __shared__ float cpart[4][AA];
  __shared__ float red_m[16], red_s[16];
  __shared__ float rv[16];
  __shared__ int   ri[16];
  __shared__ int   pred_s;

  const int b = blockIdx.x;
  const int tid = threadIdx.x;
  const int lane = tid & 63;
  const int wvi = tid >> 6;
  const int len = enc[b];
  const float ptf = decode_ptf(ptfp);

  if (tid < AA){ h_s[tid]=0.f; c_s[tid]=0.f; ctx_s[tid]=0.f; }
  if (tid == 0) pred_s = 0;
  __syncthreads();

  for (int t=0; t<TO; ++t){
    const int m = b*TO + t;
    const bool tf = (u[t] < ptf);
    float acc;
    if (tf){
      acc = XG[(size_t)m*G4 + tid];
    } else {
      if (tid < EE) x_s[tid] = embW[(size_t)pred_s*EE + tid];
      __syncthreads();
      acc = bih[tid] + bhh[tid];
      #pragma unroll 4
      for (int e=0;e<EE;++e) acc += x_s[e]*WihxT[(size_t)e*G4 + tid];
      __syncthreads();
    }
    {
      const float* wc = WihcT + tid;
      const float* wh = WhhT + tid;
      #pragma unroll 4
      for (int a=0;a<AA;++a){
        acc += wc[(size_t)a*G4]*ctx_s[a] + wh[(size_t)a*G4]*h_s[a];
      }
    }
    g_s[tid] = acc;
    __syncthreads();

    if (tid < AA){
      float gi=g_s[tid], gf=g_s[AA+tid], gg=g_s[2*AA+tid], go=g_s[3*AA+tid];
      float cn = sigm(gf)*c_s[tid] + sigm(gi)*tanhf(gg);
      float hn = sigm(go)*tanhf(cn);
      c_s[tid]=cn; h_s[tid]=hn;
      HCT[(size_t)tid*MM + m] = hn;
    }
    __syncthreads();

    // energy over t' = tid (skip t' >= len entirely)
    float ev;
    if (tid < len){
      float e0 = 0.f;
      const float* kb = kT + (size_t)b*AA*KTP + tid;
      #pragma unroll 4
      for (int a=0;a<AA;++a) e0 += kb[(size_t)a*KTP] * h_s[a];
      ev = e0;
    } else {
      ev = NEGE;
    }
    float mx = ev;
    #pragma unroll
    for (int o=1;o<64;o<<=1) mx = fmaxf(mx, __shfl_xor(mx,o));
    if (lane==0) red_m[wvi] = mx;
    __syncthreads();
    float M = red_m[0];
    #pragma unroll
    for (int i2=1;i2<16;++i2) M = fmaxf(M, red_m[i2]);
    float p = expf(ev - M);          // masked -> underflows to 0
    p_s[tid] = p;
    float sv = p;
    #pragma unroll
    for (int o=1;o<64;o<<=1) sv += __shfl_xor(sv,o);
    if (lane==0) red_s[wvi] = sv;
    __syncthreads();
    float S = 0.f;
    #pragma unroll
    for (int i2=0;i2<16;++i2) S += red_s[i2];

    // ctx: 4 quarters of t' range per attention dim a
    {
      int a = tid & (AA-1), q = tid >> 8;
      int qn = (len + 3) >> 2;
      int t0 = q*qn, t1 = min(t0+qn, len);
      float cacc = 0.f;
      const float* vb = v + (size_t)b*TD*AA + a;
      for (int tt=t0; tt<t1; ++tt) cacc += p_s[tt]*vb[(size_t)tt*AA];
      cpart[q][a] = cacc;
    }
    __syncthreads();
    if (tid < AA){
      float cv = (cpart[0][tid]+cpart[1][tid]+cpart[2][tid]+cpart[3][tid])/S;
      ctx_s[tid] = cv;
      HCT[(size_t)(AA+tid)*MM + m] = cv;
    }
    __syncthreads();

    // pred needed only if next step is not teacher-forced (never with given inputs)
    const bool need_pred = (t+1<TO) && !(u[t+1] < ptf);
    if (need_pred){
      if (tid < AA){ hc_s[tid]=h_s[tid]; hc_s[AA+tid]=ctx_s[tid]; }
      __syncthreads();
      float bvv = -3.4e38f; int bii = 0;
      for (int r=0;r<8;++r){
        int vg = tid*8 + r;
        float a2 = charb[vg];
        const float* er = embW + (size_t)vg*EE;
        for (int e=0;e<EE;++e) a2 += er[e]*hc_s[e];
        if (a2 > bvv){ bvv=a2; bii=vg; }
      }
      #pragma unroll
      for (int o=1;o<64;o<<=1){
        float ov = __shfl_xor(bvv,o); int oi = __shfl_xor(bii,o);
        if (ov > bvv || (ov == bvv && oi < bii)){ bvv=ov; bii=oi; }
      }
      if (lane==0){ rv[wvi]=bvv; ri[wvi]=bii; }
      __syncthreads();
      if (tid==0){
        float fv=rv[0]; int fi=ri[0];
        for (int w2=1;w2<16;++w2){
          if (rv[w2]>fv || (rv[w2]==fv && ri[w2]<fi)){ fv=rv[w2]; fi=ri[w2]; }
        }
        pred_s = fi;
      }
      __syncthreads();
    }
  }
}

// ---- logits[m][v] = HC[m][:]·emb[v][:] + char_b[v], written fp32 to (B,V,To)
__global__ __launch_bounds__(256) void klogits(const float* __restrict__ HCT,
      const float* __restrict__ embW, const float* __restrict__ charb,
      float* __restrict__ out)
{
  __shared__ float Ws[64][68];           // [kk][v], 16B-aligned rows
  const int vb = blockIdx.x;             // 0..127
  const int mb = blockIdx.y;             // 0..49
  const int tid = threadIdx.x;
  const int m = mb*256 + tid;
  float acc[64];
  #pragma unroll
  for (int i=0;i<64;++i) acc[i]=0.f;
  for (int kc=0; kc<EE; kc+=64){
    {
      int v0 = tid >> 2;
      int q  = tid & 3;
      const float4* src = (const float4*)(embW + (size_t)(vb*64+v0)*EE + kc + q*16);
      float4 a4 = src[0], b4 = src[1], c4 = src[2], d4 = src[3];
      int k0 = q*16;
      Ws[k0+ 0][v0]=a4.x; Ws[k0+ 1][v0]=a4.y; Ws[k0+ 2][v0]=a4.z; Ws[k0+ 3][v0]=a4.w;
      Ws[k0+ 4][v0]=b4.x; Ws[k0+ 5][v0]=b4.y; Ws[k0+ 6][v0]=b4.z; Ws[k0+ 7][v0]=b4.w;
      Ws[k0+ 8][v0]=c4.x; Ws[k0+ 9][v0]=c4.y; Ws[k0+10][v0]=c4.z; Ws[k0+11][v0]=c4.w;
      Ws[k0+12][v0]=d4.x; Ws[k0+13][v0]=d4.y; Ws[k0+14][v0]=d4.z; Ws[k0+15][v0]=d4.w;
    }
    __syncthreads();
    for (int kk=0;kk<64;++kk){
      float x = HCT[(size_t)(kc+kk)*MM + m];
      const float4* wr = (const float4*)(&Ws[kk][0]);
      #pragma unroll
      for (int i4=0;i4<16;++i4){
        float4 w4 = wr[i4];
        acc[i4*4+0] += x*w4.x; acc[i4*4+1] += x*w4.y;
        acc[i4*4+2] += x*w4.z; acc[i4*4+3] += x*w4.w;
      }
    }
    __syncthreads();
  }
  const int bb = m / TO;
  const int tt = m - bb*TO;
  #pragma unroll 4
  for (int vv2=0; vv2<64; ++vv2){
    int vg = vb*64 + vv2;
    float r = acc[vv2] + charb[vg];
    out[((size_t)bb*VV + vg)*TO + tt] = r;
  }
}

extern "C" void kernel_launch(void* const* d_in, const int* in_sizes, int n_in,
                              void* d_out, int out_size, void* d_ws, size_t ws_size,
                              hipStream_t stream)
{
  const float* k    = (const float*)d_in[0];
  const float* v    = (const float*)d_in[1];
  const int*   enc  = (const int*)d_in[2];
  const int*   gt   = (const int*)d_in[3];
  const void*  ptf  = d_in[4];
  const float* embW = (const float*)d_in[5];
  const float* Wih  = (const float*)d_in[6];
  const float* Whh  = (const float*)d_in[7];
  const float* bih  = (const float*)d_in[8];
  const float* bhh  = (const float*)d_in[9];
  const float* chb  = (const float*)d_in[10];
  const float* u    = (const float*)d_in[11];
  float* out = (float*)d_out;

  float* ws    = (float*)d_ws;
  float* XG    = ws;                       // 12800*1024
  float* kT    = XG    + (size_t)MM*G4;    // 32*256*1024
  float* HCT   = kT    + (size_t)BB*AA*KTP;// 512*12800
  float* WihcT = HCT   + (size_t)EE*MM;    // 256*1024
  float* WhhT  = WihcT + (size_t)AA*G4;    // 256*1024
  float* WihxT = WhhT  + (size_t)AA*G4;    // 512*1024

  kprep_w  <<<1024, 256, 0, stream>>>(Wih, Whh, WihcT, WhhT, WihxT);
  kprep_kT <<<8192, 256, 0, stream>>>(k, kT);
  kxg      <<<dim3(800,4), 256, 0, stream>>>(gt, embW, WihxT, bih, bhh, XG);
  kseq     <<<32, 1024, 0, stream>>>(kT, v, enc, gt, ptf, embW, bih, bhh, chb, u,
                                     XG, WihcT, WhhT, WihxT, HCT);
  klogits  <<<dim3(128,50), 256, 0, stream>>>(HCT, embW, chb, out);
}

// Round 3
// 16198.808 us; speedup vs baseline: 2.5020x; 2.5020x over previous
//
#include <hip/hip_runtime.h>
#include <hip/hip_bf16.h>

#define BB 32
#define TD 800
#define TO 400
#define AA 256
#define EE 512
#define VV 8192
#define G4 1024
#define MM (BB*TO)        // 12800
#define NEGE -1e9f
#define KTP 1024          // padded Td for kT

__device__ __forceinline__ float sigm(float x){ return 1.f/(1.f+expf(-x)); }

__device__ __forceinline__ float decode_ptf(const void* p){
  int w = *(const int*)p;
  if (w >= 0 && w < 1048576) return (float)w;   // int-encoded small scalar
  return __int_as_float(w);                      // fp32-encoded
}

// ---- WcatT[k][j]: k<256 -> Wih[j][512+k] (ctx), k in[256,512) -> Whh[j][k-256] (h)
//      WihxT[e][j] = Wih[j][e]
__global__ void kprep_w(const float* __restrict__ Wih, const float* __restrict__ Whh,
                        float* __restrict__ WcatT, float* __restrict__ WihxT){
  int id = blockIdx.x*blockDim.x + threadIdx.x;
  const int total = EE*G4 + EE*G4;
  for (; id < total; id += gridDim.x*blockDim.x){
    if (id < EE*G4){
      int kk = id >> 10, j = id & 1023;
      WcatT[id] = (kk < AA) ? Wih[j*768 + EE + kk] : Whh[j*AA + (kk-AA)];
    } else {
      int i2 = id - EE*G4;
      int e = i2 >> 10, j = i2 & 1023;
      WihxT[i2] = Wih[j*768 + e];
    }
  }
}

// ---- kT[b][a][t] = k[b][t][a], zero-padded to t<1024
__global__ void kprep_kT(const float* __restrict__ k, float* __restrict__ kT){
  int id = blockIdx.x*blockDim.x + threadIdx.x;
  const int total = BB*AA*KTP;
  for (; id < total; id += gridDim.x*blockDim.x){
    int t = id & (KTP-1);
    int rest = id >> 10;
    int a = rest & (AA-1);
    int b = rest >> 8;
    kT[id] = (t < TD) ? k[(b*TD + t)*AA + a] : 0.f;
  }
}

// ---- XG[m][j] = sum_e emb[gt[m]][e]*WihxT[e][j] + b_ih[j] + b_hh[j]
__global__ __launch_bounds__(256) void kxg(const int* __restrict__ gt,
                     const float* __restrict__ embW,
                     const float* __restrict__ WihxT, const float* __restrict__ bih,
                     const float* __restrict__ bhh, float* __restrict__ XG){
  __shared__ float Xs[16][64];
  __shared__ int toks[16];
  const int m0 = blockIdx.x * 16;
  const int j0 = blockIdx.y * 256 + (threadIdx.x & 63)*4;
  const int r0 = (threadIdx.x >> 6) * 4;
  float acc[4][4];
  #pragma unroll
  for (int r=0;r<4;++r){ acc[r][0]=acc[r][1]=acc[r][2]=acc[r][3]=0.f; }
  if (threadIdx.x < 16) toks[threadIdx.x] = gt[m0 + threadIdx.x];
  __syncthreads();
  for (int kc=0; kc<EE; kc+=64){
    {
      int lr = threadIdx.x >> 4;     // 0..15 row
      int lq = threadIdx.x & 15;     // 0..15 quad
      const float4 xv = *(const float4*)(embW + (size_t)toks[lr]*EE + kc + lq*4);
      Xs[lr][lq*4+0]=xv.x; Xs[lr][lq*4+1]=xv.y; Xs[lr][lq*4+2]=xv.z; Xs[lr][lq*4+3]=xv.w;
    }
    __syncthreads();
    #pragma unroll 4
    for (int kk=0; kk<64; ++kk){
      const float4 wv = *(const float4*)(WihxT + (size_t)(kc+kk)*G4 + j0);
      #pragma unroll
      for (int r=0;r<4;++r){
        float xs = Xs[r0+r][kk];
        acc[r][0] += wv.x*xs; acc[r][1] += wv.y*xs;
        acc[r][2] += wv.z*xs; acc[r][3] += wv.w*xs;
      }
    }
    __syncthreads();
  }
  const float4 b1 = *(const float4*)(bih + j0);
  const float4 b2 = *(const float4*)(bhh + j0);
  #pragma unroll
  for (int r=0;r<4;++r){
    float4 o4 = make_float4(acc[r][0]+b1.x+b2.x, acc[r][1]+b1.y+b2.y,
                            acc[r][2]+b1.z+b2.z, acc[r][3]+b1.w+b2.w);
    *(float4*)(XG + (size_t)(m0+r0+r)*G4 + j0) = o4;
  }
}

// ---- sequential recurrence, one block per batch element, float4 + K-split ILP
__global__ __launch_bounds__(1024) void kseq(
    const float* __restrict__ kT, const float* __restrict__ v,
    const int* __restrict__ enc, const int* __restrict__ gt,
    const void* __restrict__ ptfp, const float* __restrict__ embW,
    const float* __restrict__ bih, const float* __restrict__ bhh,
    const float* __restrict__ charb, const float* __restrict__ u,
    const float* __restrict__ XG, const float* __restrict__ WcatT,
    const float* __restrict__ WihxT, float* __restrict__ HCT)
{
  __shared__ float s_s[EE];        // [ctx(0..255) || h(256..511)]
  __shared__ float c_s[AA];
  __shared__ float part[4*G4];     // 16KB: gpart/epart [4][1024], cpart [16][256]
  __shared__ float p_s[KTP];       // softmax probs; also fallback xg buffer
  __shared__ float x_s[EE];
  __shared__ float red_m[16], red_s[16];
  __shared__ float rv[16];
  __shared__ int   ri[16];
  __shared__ int   pred_s;

  const int b = blockIdx.x;
  const int tid = threadIdx.x;
  const int lane = tid & 63;
  const int wvi = tid >> 6;
  const int len = enc[b];
  const float ptf = decode_ptf(ptfp);

  if (tid < AA){ s_s[tid]=0.f; s_s[AA+tid]=0.f; c_s[tid]=0.f; }
  if (tid == 0) pred_s = 0;
  __syncthreads();

  const int jq = tid & 255;        // output float4 index (gates)
  const int kq = tid >> 8;         // K quarter
  const int tq = tid & 255;        // t' float4 group (energy)
  const int aq = tid >> 8;         // a quarter (energy)
  const int a4 = tid & 63;         // a float4 index (ctx)
  const int tg = tid >> 6;         // t group 0..15 (ctx)

  for (int t=0; t<TO; ++t){
    const int m = b*TO + t;
    const bool tf = (u[t] < ptf);

    if (!tf){
      // fallback (never taken with p_tf=1): xg into p_s
      if (tid < EE) x_s[tid] = embW[(size_t)pred_s*EE + tid];
      __syncthreads();
      float a0 = bih[tid] + bhh[tid];
      for (int e=0;e<EE;++e) a0 += x_s[e]*WihxT[(size_t)e*G4 + tid];
      p_s[tid] = a0;
      __syncthreads();
    }

    // ---- gates partials: part[kq][j] = sum_{k in quarter} Wcat[k][j]*s[k]
    {
      const float4* wp = (const float4*)(WcatT + (size_t)(kq*128)*G4) + jq;
      const float* sp = s_s + kq*128;
      float4 ac0 = make_float4(0,0,0,0), ac1 = make_float4(0,0,0,0);
      #pragma unroll 4
      for (int kk=0; kk<128; kk+=2){
        float4 w0 = wp[0];
        float4 w1 = wp[256];
        wp += 512;
        float sv0 = sp[kk], sv1 = sp[kk+1];
        ac0.x += w0.x*sv0; ac0.y += w0.y*sv0; ac0.z += w0.z*sv0; ac0.w += w0.w*sv0;
        ac1.x += w1.x*sv1; ac1.y += w1.y*sv1; ac1.z += w1.z*sv1; ac1.w += w1.w*sv1;
      }
      float4 ac = make_float4(ac0.x+ac1.x, ac0.y+ac1.y, ac0.z+ac1.z, ac0.w+ac1.w);
      *(float4*)(part + (size_t)kq*G4 + jq*4) = ac;
    }
    __syncthreads();

    // ---- LSTM pointwise (gate j: i=a, f=256+a, g=512+a, o=768+a)
    if (tid < AA){
      float bi_, bf_, bg_, bo_;
      if (tf){
        const float* xb = XG + (size_t)m*G4;
        bi_ = xb[tid]; bf_ = xb[AA+tid]; bg_ = xb[2*AA+tid]; bo_ = xb[3*AA+tid];
      } else {
        bi_ = p_s[tid]; bf_ = p_s[AA+tid]; bg_ = p_s[2*AA+tid]; bo_ = p_s[3*AA+tid];
      }
      float gi = bi_ + part[tid]        + part[G4+tid]        + part[2*G4+tid]        + part[3*G4+tid];
      float gf = bf_ + part[AA+tid]     + part[G4+AA+tid]     + part[2*G4+AA+tid]     + part[3*G4+AA+tid];
      float gg = bg_ + part[2*AA+tid]   + part[G4+2*AA+tid]   + part[2*G4+2*AA+tid]   + part[3*G4+2*AA+tid];
      float go = bo_ + part[3*AA+tid]   + part[G4+3*AA+tid]   + part[2*G4+3*AA+tid]   + part[3*G4+3*AA+tid];
      float cn = sigm(gf)*c_s[tid] + sigm(gi)*tanhf(gg);
      float hn = sigm(go)*tanhf(cn);
      c_s[tid] = cn;
      s_s[AA+tid] = hn;
      HCT[(size_t)tid*MM + m] = hn;
    }
    __syncthreads();

    // ---- energy partials: part[aq][t'] over 4 consecutive t' per thread
    {
      const int t4 = tq*4;
      float4 ac0 = make_float4(0,0,0,0), ac1 = make_float4(0,0,0,0);
      if (t4 < len){
        const float4* kp = (const float4*)(kT + (size_t)b*AA*KTP + (size_t)(aq*64)*KTP) + tq;
        const float* hp = s_s + AA + aq*64;
        #pragma unroll 4
        for (int aa=0; aa<64; aa+=2){
          float4 k0 = kp[0];
          float4 k1 = kp[256];
          kp += 512;
          float h0 = hp[aa], h1 = hp[aa+1];
          ac0.x += k0.x*h0; ac0.y += k0.y*h0; ac0.z += k0.z*h0; ac0.w += k0.w*h0;
          ac1.x += k1.x*h1; ac1.y += k1.y*h1; ac1.z += k1.z*h1; ac1.w += k1.w*h1;
        }
      }
      float4 ac = make_float4(ac0.x+ac1.x, ac0.y+ac1.y, ac0.z+ac1.z, ac0.w+ac1.w);
      *(float4*)(part + (size_t)aq*G4 + tq*4) = ac;
    }
    __syncthreads();

    // ---- softmax over t' = tid
    float ev = NEGE;
    if (tid < len) ev = part[tid] + part[G4+tid] + part[2*G4+tid] + part[3*G4+tid];
    float mx = ev;
    #pragma unroll
    for (int o=1;o<64;o<<=1) mx = fmaxf(mx, __shfl_xor(mx,o));
    if (lane==0) red_m[wvi] = mx;
    __syncthreads();
    float M = red_m[0];
    #pragma unroll
    for (int i2=1;i2<16;++i2) M = fmaxf(M, red_m[i2]);
    float p = expf(ev - M);          // masked -> 0
    p_s[tid] = p;
    float sv = p;
    #pragma unroll
    for (int o=1;o<64;o<<=1) sv += __shfl_xor(sv,o);
    if (lane==0) red_s[wvi] = sv;
    __syncthreads();
    float S = 0.f;
    #pragma unroll
    for (int i2=0;i2<16;++i2) S += red_s[i2];

    // ---- ctx partials: part[tg][a] via float4 over a, strided t
    {
      float4 ac = make_float4(0,0,0,0);
      const float4* vp = (const float4*)(v + (size_t)b*TD*AA) + a4;
      #pragma unroll 4
      for (int tt=tg; tt<len; tt+=16){
        float4 vv = vp[(size_t)tt*64];
        float pp = p_s[tt];
        ac.x += vv.x*pp; ac.y += vv.y*pp; ac.z += vv.z*pp; ac.w += vv.w*pp;
      }
      *(float4*)(part + (size_t)tg*AA + a4*4) = ac;
    }
    __syncthreads();
    if (tid < AA){
      float cv = 0.f;
      #pragma unroll
      for (int q=0;q<16;++q) cv += part[q*AA + tid];
      cv /= S;
      s_s[tid] = cv;
      HCT[(size_t)(AA+tid)*MM + m] = cv;
    }
    __syncthreads();

    // ---- pred needed only if next step is not teacher-forced (never here)
    const bool need_pred = (t+1<TO) && !(u[t+1] < ptf);
    if (need_pred){
      float bvv = -3.4e38f; int bii = 0;
      for (int r=0;r<8;++r){
        int vg = tid*8 + r;
        float a2 = charb[vg];
        const float* er = embW + (size_t)vg*EE;
        for (int e=0;e<AA;++e) a2 += er[e]*s_s[AA+e];       // h part
        for (int e=0;e<AA;++e) a2 += er[AA+e]*s_s[e];       // ctx part
        if (a2 > bvv){ bvv=a2; bii=vg; }
      }
      #pragma unroll
      for (int o=1;o<64;o<<=1){
        float ov = __shfl_xor(bvv,o); int oi = __shfl_xor(bii,o);
        if (ov > bvv || (ov == bvv && oi < bii)){ bvv=ov; bii=oi; }
      }
      if (lane==0){ rv[wvi]=bvv; ri[wvi]=bii; }
      __syncthreads();
      if (tid==0){
        float fv=rv[0]; int fi=ri[0];
        for (int w2=1;w2<16;++w2){
          if (rv[w2]>fv || (rv[w2]==fv && ri[w2]<fi)){ fv=rv[w2]; fi=ri[w2]; }
        }
        pred_s = fi;
      }
      __syncthreads();
    }
  }
}

// ---- logits[m][v] = HC[m][:]·emb[v][:] + char_b[v], written fp32 to (B,V,To)
__global__ __launch_bounds__(256) void klogits(const float* __restrict__ HCT,
      const float* __restrict__ embW, const float* __restrict__ charb,
      float* __restrict__ out)
{
  __shared__ float Ws[64][68];           // [kk][v], 16B-aligned rows
  const int vb = blockIdx.x;             // 0..127
  const int mb = blockIdx.y;             // 0..49
  const int tid = threadIdx.x;
  const int m = mb*256 + tid;
  float acc[64];
  #pragma unroll
  for (int i=0;i<64;++i) acc[i]=0.f;
  for (int kc=0; kc<EE; kc+=64){
    {
      int v0 = tid >> 2;
      int q  = tid & 3;
      const float4* src = (const float4*)(embW + (size_t)(vb*64+v0)*EE + kc + q*16);
      float4 a4 = src[0], b4 = src[1], c4 = src[2], d4 = src[3];
      int k0 = q*16;
      Ws[k0+ 0][v0]=a4.x; Ws[k0+ 1][v0]=a4.y; Ws[k0+ 2][v0]=a4.z; Ws[k0+ 3][v0]=a4.w;
      Ws[k0+ 4][v0]=b4.x; Ws[k0+ 5][v0]=b4.y; Ws[k0+ 6][v0]=b4.z; Ws[k0+ 7][v0]=b4.w;
      Ws[k0+ 8][v0]=c4.x; Ws[k0+ 9][v0]=c4.y; Ws[k0+10][v0]=c4.z; Ws[k0+11][v0]=c4.w;
      Ws[k0+12][v0]=d4.x; Ws[k0+13][v0]=d4.y; Ws[k0+14][v0]=d4.z; Ws[k0+15][v0]=d4.w;
    }
    __syncthreads();
    for (int kk=0;kk<64;++kk){
      float x = HCT[(size_t)(kc+kk)*MM + m];
      const float4* wr = (const float4*)(&Ws[kk][0]);
      #pragma unroll
      for (int i4=0;i4<16;++i4){
        float4 w4 = wr[i4];
        acc[i4*4+0] += x*w4.x; acc[i4*4+1] += x*w4.y;
        acc[i4*4+2] += x*w4.z; acc[i4*4+3] += x*w4.w;
      }
    }
    __syncthreads();
  }
  const int bb = m / TO;
  const int tt = m - bb*TO;
  #pragma unroll 4
  for (int vv2=0; vv2<64; ++vv2){
    int vg = vb*64 + vv2;
    float r = acc[vv2] + charb[vg];
    out[((size_t)bb*VV + vg)*TO + tt] = r;
  }
}

extern "C" void kernel_launch(void* const* d_in, const int* in_sizes, int n_in,
                              void* d_out, int out_size, void* d_ws, size_t ws_size,
                              hipStream_t stream)
{
  const float* k    = (const float*)d_in[0];
  const float* v    = (const float*)d_in[1];
  const int*   enc  = (const int*)d_in[2];
  const int*   gt   = (const int*)d_in[3];
  const void*  ptf  = d_in[4];
  const float* embW = (const float*)d_in[5];
  const float* Wih  = (const float*)d_in[6];
  const float* Whh  = (const float*)d_in[7];
  const float* bih  = (const float*)d_in[8];
  const float* bhh  = (const float*)d_in[9];
  const float* chb  = (const float*)d_in[10];
  const float* u    = (const float*)d_in[11];
  float* out = (float*)d_out;

  float* ws    = (float*)d_ws;
  float* XG    = ws;                       // 12800*1024
  float* kT    = XG    + (size_t)MM*G4;    // 32*256*1024
  float* HCT   = kT    + (size_t)BB*AA*KTP;// 512*12800
  float* WcatT = HCT   + (size_t)EE*MM;    // 512*1024
  float* WihxT = WcatT + (size_t)EE*G4;    // 512*1024

  kprep_w  <<<1024, 256, 0, stream>>>(Wih, Whh, WcatT, WihxT);
  kprep_kT <<<8192, 256, 0, stream>>>(k, kT);
  kxg      <<<dim3(800,4), 256, 0, stream>>>(gt, embW, WihxT, bih, bhh, XG);
  kseq     <<<32, 1024, 0, stream>>>(kT, v, enc, gt, ptf, embW, bih, bhh, chb, u,
                                     XG, WcatT, WihxT, HCT);
  klogits  <<<dim3(128,50), 256, 0, stream>>>(HCT, embW, chb, out);
}